// Round 6
// baseline (454.106 us; speedup 1.0000x reference)
//
#include <hip/hip_runtime.h>
#include <cmath>

// Sampler: B=256 rows, V=128000 vocab.
// out[0..255]         = tokens (as float values)
// out[256..256+B*V)   = final probs (min-p renormalized), mostly zeros
//
// Structure (all proven-fast memory shapes, no per-wave MLP needed):
//   hipMemsetAsync: zero counters (1KB) and the whole output (131MB,
//                   runtime fill path = 6.6 TB/s store-only).
//   k_gather: PURE READ, one float4 per thread (m13 copy shape, max TLP):
//             gather candidates (l >= 6.0, ~173/row, CAP=512 = 22 sigma)
//             into per-row global lists via atomics (~44K total).
//   k_select: one block/row: candidates -> LDS, wave-0 register top-64
//             extraction + exact top-k/top-p/min-p/inverse-CDF math +
//             scatter. Bisection rescan fallback if count outside [64,CAP].
//
// Exactness: softmax Z cancels in every renorm. With count>=64, elements
// below the threshold cannot reach the top-64, so reference top-k zeroes
// them -> candidate-only math is exact. Max candidate == row max.

constexpr int BB  = 256;
constexpr int VV  = 128000;
constexpr int CAP = 512;
constexpr int IPL = CAP / 64;            // 8 items/lane in extraction
constexpr int NV4_ROW = VV / 4;          // 32000 float4 per row
constexpr int GA_BLOCKS = BB * NV4_ROW / 256;   // 32000 blocks, 1 float4/thread
constexpr float T0 = 6.0f;

__global__ __launch_bounds__(256) void k_gather(
    const float* __restrict__ logits, int* __restrict__ gcnt,
    float* __restrict__ gcl, int* __restrict__ gix) {
  const int idx = blockIdx.x * 256 + threadIdx.x;   // [0, 8,192,000)
  const int row = idx / NV4_ROW;                    // magic-mul (const divisor)
  const int col = (idx - row * NV4_ROW) << 2;
  const float4 v = reinterpret_cast<const float4*>(logits)[idx];
  if (v.x >= T0 || v.y >= T0 || v.z >= T0 || v.w >= T0) {   // ~1/3 of waves
    if (v.x >= T0) { int p = atomicAdd(&gcnt[row], 1); if (p < CAP) { gcl[row*CAP+p] = v.x; gix[row*CAP+p] = col;     } }
    if (v.y >= T0) { int p = atomicAdd(&gcnt[row], 1); if (p < CAP) { gcl[row*CAP+p] = v.y; gix[row*CAP+p] = col + 1; } }
    if (v.z >= T0) { int p = atomicAdd(&gcnt[row], 1); if (p < CAP) { gcl[row*CAP+p] = v.z; gix[row*CAP+p] = col + 2; } }
    if (v.w >= T0) { int p = atomicAdd(&gcnt[row], 1); if (p < CAP) { gcl[row*CAP+p] = v.w; gix[row*CAP+p] = col + 3; } }
  }
}

__global__ __launch_bounds__(256) void k_select(
    const float* __restrict__ logits, const float* __restrict__ temps,
    const int* __restrict__ topks, const float* __restrict__ topps,
    const float* __restrict__ minps, const float* __restrict__ noise,
    const int* __restrict__ gcnt, const float* __restrict__ gcl,
    const int* __restrict__ gix, float* __restrict__ out) {
  const int row = blockIdx.x;
  const int tid = threadIdx.x;
  float* orow = out + BB + (size_t)row * VV;

  __shared__ float cl[CAP];
  __shared__ int   ci[CAP];
  __shared__ int   s_cnt;
  __shared__ float s_t, s_lo, s_hi;

  int cnt = gcnt[row];
  const int n0 = min(cnt, CAP);
  for (int i = tid; i < n0; i += 256) { cl[i] = gcl[row*CAP+i]; ci[i] = gix[row*CAP+i]; }
  __syncthreads();

  // ---- fallback bisection rescan (never triggers on bench data) ----
  if (cnt < 64 || cnt > CAP) {
    const float4* lp4 = reinterpret_cast<const float4*>(logits + (size_t)row * VV);
    if (tid == 0) { s_lo = (cnt > CAP) ? T0 : -1e30f; s_hi = (cnt > CAP) ? 1e30f : T0; }
    __syncthreads();
    for (int it = 0; it < 48 && (cnt < 64 || cnt > CAP); ++it) {
      if (tid == 0) {
        const float lo = s_lo, hi = s_hi;
        s_t = (lo <= -1e29f) ? hi - 8.0f : (hi >= 1e29f ? lo + 8.0f : 0.5f * (lo + hi));
        s_cnt = 0;
      }
      __syncthreads();
      const float t = s_t;
      for (int j = tid; j < NV4_ROW; j += 256) {
        const float4 v = lp4[j]; const int base = j << 2;
        if (v.x >= t) { int p = atomicAdd(&s_cnt, 1); if (p < CAP) { cl[p] = v.x; ci[p] = base;     } }
        if (v.y >= t) { int p = atomicAdd(&s_cnt, 1); if (p < CAP) { cl[p] = v.y; ci[p] = base + 1; } }
        if (v.z >= t) { int p = atomicAdd(&s_cnt, 1); if (p < CAP) { cl[p] = v.z; ci[p] = base + 2; } }
        if (v.w >= t) { int p = atomicAdd(&s_cnt, 1); if (p < CAP) { cl[p] = v.w; ci[p] = base + 3; } }
      }
      __syncthreads();
      cnt = s_cnt;
      if (tid == 0) { if (cnt > CAP) s_lo = s_t; else if (cnt < 64) s_hi = s_t; }
      __syncthreads();
    }
  }
  const int n = min(cnt, CAP);

  // ---- wave 0: register top-64 extraction + exact selection math ----
  if (tid < 64) {
    const int lane = tid;
    float rv[IPL]; int rix[IPL];
#pragma unroll
    for (int q = 0; q < IPL; ++q) {
      const int idx = lane + (q << 6);
      const bool ok = idx < n;
      rv[q]  = ok ? cl[idx] : -INFINITY;
      rix[q] = ok ? ci[idx] : 0x7fffffff;
    }
    const int n64 = min(n, 64);
    float lv = 0.0f; int iv = 0x7fffffff;
    for (int r = 0; r < n64; ++r) {          // uniform trip count
      float bv = rv[0]; int bi = rix[0];
#pragma unroll
      for (int q = 1; q < IPL; ++q) if (rv[q] > bv) { bv = rv[q]; bi = rix[q]; }
      for (int o = 32; o > 0; o >>= 1) {
        const float ov = __shfl_xor(bv, o, 64);
        const int   oi = __shfl_xor(bi, o, 64);
        if (ov > bv || (ov == bv && oi < bi)) { bv = ov; bi = oi; }
      }
#pragma unroll
      for (int q = 0; q < IPL; ++q) if (rix[q] == bi) { rv[q] = -INFINITY; rix[q] = 0x7fffffff; }
      if (lane == r) { lv = bv; iv = bi; }   // lane r owns r-th largest
    }

    const float Tv = temps[row];
    const float Mx = __shfl(lv, 0, 64) / Tv; // lane0 lv == row max; /T>0 monotone
    const bool valid = lane < n64;
    const float p = valid ? expf(lv / Tv - Mx) : 0.0f;   // Z cancels everywhere

    int k = topks[row];
    k = max(1, min(k, n64));
    const float kth = __shfl(p, k - 1, 64);
    const bool keepA = valid && (p >= kth);              // top-k (with ties)
    float S1 = keepA ? p : 0.0f;
    for (int o = 32; o > 0; o >>= 1) S1 += __shfl_xor(S1, o, 64);
    const float q = keepA ? (p / S1) : 0.0f;

    // top-p: keep while exclusive-cumsum < top_p; then q >= (min kept q)
    float cs = q;
    for (int o = 1; o < 64; o <<= 1) { const float v = __shfl_up(cs, o, 64); if (lane >= o) cs += v; }
    const float lhs = cs - q;                            // mimics (csum - sorted)
    const bool keepBp = keepA && (lhs < topps[row]);
    float thr = keepBp ? q : INFINITY;
    for (int o = 32; o > 0; o >>= 1) thr = fminf(thr, __shfl_xor(thr, o, 64));
    const bool keepB = keepA && (q >= thr);
    float S2 = keepB ? q : 0.0f;
    for (int o = 32; o > 0; o >>= 1) S2 += __shfl_xor(S2, o, 64);
    const float r2 = keepB ? (q / S2) : 0.0f;

    // min-p
    const float r0 = __shfl(r2, 0, 64);                  // lane 0 = max prob
    const bool keepC = keepB && (r2 >= minps[row] * r0);
    float S3 = keepC ? r2 : 0.0f;
    for (int o = 32; o > 0; o >>= 1) S3 += __shfl_xor(S3, o, 64);
    const float f = keepC ? (r2 / S3) : 0.0f;            // final probs

    // inverse-CDF sample in token-index order (zeros are fp no-ops)
    float cum = 0.0f, tot = 0.0f;
    for (int i2 = 0; i2 < 64; ++i2) {
      const float fi = __shfl(f, i2, 64);
      const int   ii = __shfl(iv, i2, 64);
      tot += fi;
      if (ii <= iv) cum += fi;             // same add sequence as tot at max-idx lane
    }
    const float target = noise[row] * tot;
    int tok = 0;                            // target<=0 -> argmax(cdf>=0) = 0
    if (target > 0.0f) {
      int cand = (keepC && cum >= target) ? iv : 0x7fffffff;
      for (int o = 32; o > 0; o >>= 1) cand = min(cand, __shfl_xor(cand, o, 64));
      if (cand == 0x7fffffff) {            // fp safety net
        int mi = keepC ? iv : -1;
        for (int o = 32; o > 0; o >>= 1) mi = max(mi, __shfl_xor(mi, o, 64));
        cand = (mi < 0) ? 0 : mi;
      }
      tok = cand;
    }

    if (keepC) orow[iv] = f;               // ordered after memset by stream order
    if (lane == 0) out[row] = (float)tok;
  }
}

extern "C" void kernel_launch(void* const* d_in, const int* in_sizes, int n_in,
                              void* d_out, int out_size, void* d_ws, size_t ws_size,
                              hipStream_t stream) {
  const float* logits = (const float*)d_in[0];
  const float* temps  = (const float*)d_in[1];
  const int*   topks  = (const int*)d_in[2];
  const float* topps  = (const float*)d_in[3];
  const float* minps  = (const float*)d_in[4];
  const float* noise  = (const float*)d_in[5];
  float* out = (float*)d_out;

  // ws layout: [256 x int counters][256*CAP floats][256*CAP ints]  (~1.05 MB)
  int*   gcnt = (int*)d_ws;
  float* gcl  = (float*)((char*)d_ws + 256 * sizeof(int));
  int*   gix  = (int*)((char*)d_ws + 256 * sizeof(int) + (size_t)BB * CAP * sizeof(float));

  // zero counters + entire output via the runtime fill path (6.6 TB/s).
  hipMemsetAsync(gcnt, 0, 256 * sizeof(int), stream);
  hipMemsetAsync(out, 0, (size_t)out_size * sizeof(float), stream);
  k_gather<<<GA_BLOCKS, 256, 0, stream>>>(logits, gcnt, gcl, gix);
  k_select<<<BB, 256, 0, stream>>>(logits, temps, topks, topps, minps, noise,
                                   gcnt, gcl, gix, out);
}

// Round 7
// 307.585 us; speedup vs baseline: 1.4764x; 1.4764x over previous
//
#include <hip/hip_runtime.h>
#include <cmath>

// Sampler: B=256 rows, V=128000 vocab.
// out[0..255]         = tokens (as float values)
// out[256..256+B*V)   = final probs (min-p renormalized), mostly zeros
//
// hipMemsetAsync: zero counters (1KB) + whole output (131MB, runtime fill
//                 path = 6.6 TB/s proven in-harness).
// k_gather: G11-shaped grid (2000 blocks x 256 thr = 8000 waves, full
//           occupancy), 16 float4/thread.
//           Phase A: branch-free scan (load -> fmax4 -> hit bitmask). No
//           stores/branches/atomics in the load loop -> loads pipeline.
//           Phase B: only hit-flagged iterations (~8% of threads) re-load
//           from L3 and push candidates (l >= 6.0) via atomics (~44K total).
// k_select: one block/row: candidates -> LDS, wave-0 register top-64
//           extraction + exact top-k/top-p/min-p/inverse-CDF + scatter.
//           Bisection rescan fallback if count outside [64, CAP].
//
// Exactness: softmax Z cancels in every renorm. With count>=64, sub-threshold
// elements cannot reach the top-64 -> reference top-k zeroes them ->
// candidate-only math is exact. Extraction lane 0 == row max.

constexpr int BB  = 256;
constexpr int VV  = 128000;
constexpr int CAP = 512;
constexpr int IPL = CAP / 64;              // 8 items/lane in extraction
constexpr int NV4_ROW = VV / 4;            // 32000 float4 per row
constexpr int GB_BLOCKS  = 2000;
constexpr int GB_THREADS = 256;
constexpr int TOTT  = GB_BLOCKS * GB_THREADS;       // 512000 threads
constexpr int ITERS = (BB * NV4_ROW) / TOTT;        // 16 float4 per thread, exact
constexpr int ROWS_PER_IT = TOTT / NV4_ROW;         // 16 rows per iteration step, exact
constexpr float T0 = 6.0f;

__global__ __launch_bounds__(GB_THREADS) void k_gather(
    const float* __restrict__ logits, int* __restrict__ gcnt,
    float* __restrict__ gcl, int* __restrict__ gix) {
  const int idx  = blockIdx.x * GB_THREADS + threadIdx.x;   // [0, 512000)
  const int row0 = idx / NV4_ROW;                           // magic-mul, once
  const int col  = (idx - row0 * NV4_ROW) << 2;             // invariant across iters
  const float4* in4 = reinterpret_cast<const float4*>(logits);

  // ---- phase A: branch-free streaming scan (loads have no side-effect
  //      consumers -> compiler free to cluster; TLP covers the rest) ----
  unsigned mask = 0;
#pragma unroll
  for (int u = 0; u < ITERS; ++u) {
    const float4 v = in4[idx + u * TOTT];
    const float m4 = fmaxf(fmaxf(v.x, v.y), fmaxf(v.z, v.w));
    mask |= (unsigned)(m4 >= T0) << u;
  }

  // ---- phase B: rare (P(hit) ~ 8%/thread), L3-resident re-reads ----
  while (mask) {
    const int u = __ffs(mask) - 1;
    mask &= mask - 1;
    const float4 v = in4[idx + u * TOTT];
    const int row = row0 + u * ROWS_PER_IT;
    if (v.x >= T0) { int p = atomicAdd(&gcnt[row], 1); if (p < CAP) { gcl[row*CAP+p] = v.x; gix[row*CAP+p] = col;     } }
    if (v.y >= T0) { int p = atomicAdd(&gcnt[row], 1); if (p < CAP) { gcl[row*CAP+p] = v.y; gix[row*CAP+p] = col + 1; } }
    if (v.z >= T0) { int p = atomicAdd(&gcnt[row], 1); if (p < CAP) { gcl[row*CAP+p] = v.z; gix[row*CAP+p] = col + 2; } }
    if (v.w >= T0) { int p = atomicAdd(&gcnt[row], 1); if (p < CAP) { gcl[row*CAP+p] = v.w; gix[row*CAP+p] = col + 3; } }
  }
}

__global__ __launch_bounds__(256) void k_select(
    const float* __restrict__ logits, const float* __restrict__ temps,
    const int* __restrict__ topks, const float* __restrict__ topps,
    const float* __restrict__ minps, const float* __restrict__ noise,
    const int* __restrict__ gcnt, const float* __restrict__ gcl,
    const int* __restrict__ gix, float* __restrict__ out) {
  const int row = blockIdx.x;
  const int tid = threadIdx.x;
  float* orow = out + BB + (size_t)row * VV;

  __shared__ float cl[CAP];
  __shared__ int   ci[CAP];
  __shared__ int   s_cnt;
  __shared__ float s_t, s_lo, s_hi;

  int cnt = gcnt[row];
  const int n0 = min(cnt, CAP);
  for (int i = tid; i < n0; i += 256) { cl[i] = gcl[row*CAP+i]; ci[i] = gix[row*CAP+i]; }
  __syncthreads();

  // ---- fallback bisection rescan (never triggers on bench data) ----
  if (cnt < 64 || cnt > CAP) {
    const float4* lp4 = reinterpret_cast<const float4*>(logits + (size_t)row * VV);
    if (tid == 0) { s_lo = (cnt > CAP) ? T0 : -1e30f; s_hi = (cnt > CAP) ? 1e30f : T0; }
    __syncthreads();
    for (int it = 0; it < 48 && (cnt < 64 || cnt > CAP); ++it) {
      if (tid == 0) {
        const float lo = s_lo, hi = s_hi;
        s_t = (lo <= -1e29f) ? hi - 8.0f : (hi >= 1e29f ? lo + 8.0f : 0.5f * (lo + hi));
        s_cnt = 0;
      }
      __syncthreads();
      const float t = s_t;
      for (int j = tid; j < NV4_ROW; j += 256) {
        const float4 v = lp4[j]; const int base = j << 2;
        if (v.x >= t) { int p = atomicAdd(&s_cnt, 1); if (p < CAP) { cl[p] = v.x; ci[p] = base;     } }
        if (v.y >= t) { int p = atomicAdd(&s_cnt, 1); if (p < CAP) { cl[p] = v.y; ci[p] = base + 1; } }
        if (v.z >= t) { int p = atomicAdd(&s_cnt, 1); if (p < CAP) { cl[p] = v.z; ci[p] = base + 2; } }
        if (v.w >= t) { int p = atomicAdd(&s_cnt, 1); if (p < CAP) { cl[p] = v.w; ci[p] = base + 3; } }
      }
      __syncthreads();
      cnt = s_cnt;
      if (tid == 0) { if (cnt > CAP) s_lo = s_t; else if (cnt < 64) s_hi = s_t; }
      __syncthreads();
    }
  }
  const int n = min(cnt, CAP);

  // ---- wave 0: register top-64 extraction + exact selection math ----
  if (tid < 64) {
    const int lane = tid;
    float rv[IPL]; int rix[IPL];
#pragma unroll
    for (int q = 0; q < IPL; ++q) {
      const int idx = lane + (q << 6);
      const bool ok = idx < n;
      rv[q]  = ok ? cl[idx] : -INFINITY;
      rix[q] = ok ? ci[idx] : 0x7fffffff;
    }
    const int n64 = min(n, 64);
    float lv = 0.0f; int iv = 0x7fffffff;
    for (int r = 0; r < n64; ++r) {          // uniform trip count
      float bv = rv[0]; int bi = rix[0];
#pragma unroll
      for (int q = 1; q < IPL; ++q) if (rv[q] > bv) { bv = rv[q]; bi = rix[q]; }
      for (int o = 32; o > 0; o >>= 1) {
        const float ov = __shfl_xor(bv, o, 64);
        const int   oi = __shfl_xor(bi, o, 64);
        if (ov > bv || (ov == bv && oi < bi)) { bv = ov; bi = oi; }
      }
#pragma unroll
      for (int q = 0; q < IPL; ++q) if (rix[q] == bi) { rv[q] = -INFINITY; rix[q] = 0x7fffffff; }
      if (lane == r) { lv = bv; iv = bi; }   // lane r owns r-th largest
    }

    const float Tv = temps[row];
    const float Mx = __shfl(lv, 0, 64) / Tv; // lane0 lv == row max; /T>0 monotone
    const bool valid = lane < n64;
    const float p = valid ? expf(lv / Tv - Mx) : 0.0f;   // Z cancels everywhere

    int k = topks[row];
    k = max(1, min(k, n64));
    const float kth = __shfl(p, k - 1, 64);
    const bool keepA = valid && (p >= kth);              // top-k (with ties)
    float S1 = keepA ? p : 0.0f;
    for (int o = 32; o > 0; o >>= 1) S1 += __shfl_xor(S1, o, 64);
    const float q = keepA ? (p / S1) : 0.0f;

    // top-p: keep while exclusive-cumsum < top_p; then q >= (min kept q)
    float cs = q;
    for (int o = 1; o < 64; o <<= 1) { const float v = __shfl_up(cs, o, 64); if (lane >= o) cs += v; }
    const float lhs = cs - q;                            // mimics (csum - sorted)
    const bool keepBp = keepA && (lhs < topps[row]);
    float thr = keepBp ? q : INFINITY;
    for (int o = 32; o > 0; o >>= 1) thr = fminf(thr, __shfl_xor(thr, o, 64));
    const bool keepB = keepA && (q >= thr);
    float S2 = keepB ? q : 0.0f;
    for (int o = 32; o > 0; o >>= 1) S2 += __shfl_xor(S2, o, 64);
    const float r2 = keepB ? (q / S2) : 0.0f;

    // min-p
    const float r0 = __shfl(r2, 0, 64);                  // lane 0 = max prob
    const bool keepC = keepB && (r2 >= minps[row] * r0);
    float S3 = keepC ? r2 : 0.0f;
    for (int o = 32; o > 0; o >>= 1) S3 += __shfl_xor(S3, o, 64);
    const float f = keepC ? (r2 / S3) : 0.0f;            // final probs

    // inverse-CDF sample in token-index order (zeros are fp no-ops)
    float cum = 0.0f, tot = 0.0f;
    for (int i2 = 0; i2 < 64; ++i2) {
      const float fi = __shfl(f, i2, 64);
      const int   ii = __shfl(iv, i2, 64);
      tot += fi;
      if (ii <= iv) cum += fi;             // same add sequence as tot at max-idx lane
    }
    const float target = noise[row] * tot;
    int tok = 0;                            // target<=0 -> argmax(cdf>=0) = 0
    if (target > 0.0f) {
      int cand = (keepC && cum >= target) ? iv : 0x7fffffff;
      for (int o = 32; o > 0; o >>= 1) cand = min(cand, __shfl_xor(cand, o, 64));
      if (cand == 0x7fffffff) {            // fp safety net
        int mi = keepC ? iv : -1;
        for (int o = 32; o > 0; o >>= 1) mi = max(mi, __shfl_xor(mi, o, 64));
        cand = (mi < 0) ? 0 : mi;
      }
      tok = cand;
    }

    if (keepC) orow[iv] = f;               // ordered after memset by stream order
    if (lane == 0) out[row] = (float)tok;
  }
}

extern "C" void kernel_launch(void* const* d_in, const int* in_sizes, int n_in,
                              void* d_out, int out_size, void* d_ws, size_t ws_size,
                              hipStream_t stream) {
  const float* logits = (const float*)d_in[0];
  const float* temps  = (const float*)d_in[1];
  const int*   topks  = (const int*)d_in[2];
  const float* topps  = (const float*)d_in[3];
  const float* minps  = (const float*)d_in[4];
  const float* noise  = (const float*)d_in[5];
  float* out = (float*)d_out;

  // ws layout: [256 x int counters][256*CAP floats][256*CAP ints]  (~1.05 MB)
  int*   gcnt = (int*)d_ws;
  float* gcl  = (float*)((char*)d_ws + 256 * sizeof(int));
  int*   gix  = (int*)((char*)d_ws + 256 * sizeof(int) + (size_t)BB * CAP * sizeof(float));

  hipMemsetAsync(gcnt, 0, 256 * sizeof(int), stream);
  k_gather<<<GB_BLOCKS, GB_THREADS, 0, stream>>>(logits, gcnt, gcl, gix);
  hipMemsetAsync(out, 0, (size_t)out_size * sizeof(float), stream);  // 6.6 TB/s fill path
  k_select<<<BB, 256, 0, stream>>>(logits, temps, topks, topps, minps, noise,
                                   gcnt, gcl, gix, out);
}